// Round 3
// baseline (313.826 us; speedup 1.0000x reference)
//
#include <hip/hip_runtime.h>
#include <cstdint>

#define HB 8
#define CM 128
#define NHEAD 8
#define NPT 8
#define DHD 16
#define HS 64
#define WS 64
#define LTOT 4096

__device__ __forceinline__ float fast_tanh(float x) {
  float e = __expf(2.0f * x);
  return 1.0f - 2.0f / (e + 1.0f);
}

// Thread-per-l GEMM, W kept uniform (scalar-loaded). C[l][n] = sum_k A.. * W[k][n] + b[n]
// A_COLS=true : A is [b][128][LTOT] (lanes coalesce along l, 4B per k)
// A_COLS=false: A is [b][LTOT][128] (thread streams its own 512B row as float4)
// OUT_MODE 0: value layout out[((b*8 + n/16)*LTOT + l)*16 + n%16]
// OUT_MODE 1: out[(b*N + n)*LTOT + l]
// Grid: (LTOT/256, N/NW, HB), block 256. acc[NW] in VGPRs.
template <int N, int NW, int OUT_MODE, bool A_COLS>
__global__ __launch_bounds__(256) void gemmv(const float* __restrict__ A,
                                             const float* __restrict__ W,
                                             const float* __restrict__ bias,
                                             float* __restrict__ out) {
  const int t = threadIdx.x;
  const int l = blockIdx.x * 256 + t;
  const int n0 = blockIdx.y * NW;
  const int b = blockIdx.z;

  float acc[NW];
#pragma unroll
  for (int j = 0; j < NW; ++j) acc[j] = 0.0f;

  if (A_COLS) {
    const float* Ap = A + (size_t)b * (CM * LTOT) + l;
#pragma unroll 2
    for (int k = 0; k < 128; ++k) {
      const float a = Ap[(size_t)k * LTOT];
#pragma unroll
      for (int j = 0; j < NW; ++j) acc[j] += a * W[k * N + n0 + j];
    }
  } else {
    const float4* Ap = (const float4*)(A + ((size_t)b * LTOT + l) * CM);
#pragma unroll 2
    for (int k4 = 0; k4 < 32; ++k4) {
      const float4 a4 = Ap[k4];
      const float av[4] = {a4.x, a4.y, a4.z, a4.w};
#pragma unroll
      for (int c = 0; c < 4; ++c) {
        const int k = k4 * 4 + c;
#pragma unroll
        for (int j = 0; j < NW; ++j) acc[j] += av[c] * W[k * N + n0 + j];
      }
    }
  }

  if (OUT_MODE == 0) {
#pragma unroll
    for (int j4 = 0; j4 < NW / 4; ++j4) {
      const int n = n0 + j4 * 4;
      float4 v = {acc[j4 * 4 + 0] + bias[n + 0], acc[j4 * 4 + 1] + bias[n + 1],
                  acc[j4 * 4 + 2] + bias[n + 2], acc[j4 * 4 + 3] + bias[n + 3]};
      float* op = out + (((size_t)b * NHEAD + (n >> 4)) * LTOT + l) * DHD + (n & 15);
      *(float4*)op = v;
    }
  } else {
#pragma unroll
    for (int j = 0; j < NW; ++j) {
      const int n = n0 + j;
      out[((size_t)b * N + n) * LTOT + l] = acc[j] + bias[n];
    }
  }
}

// Cooperative sampler: wave = one (b,l,h); lane = (sg[2],c[2],d4[2]).
// 2 iterations cover 8 points (p = sg + 4*it). Lane loads ONE float4 of its
// corner's 64B pixel line (4 lanes consume a full line -> coalesced).
// Reduction over corners+points via shfl_xor. Writes attout row-major [b][l][128].
__global__ __launch_bounds__(256) void sampler(const float* __restrict__ value,
                                               const float* __restrict__ offraw,
                                               const float* __restrict__ attnraw,
                                               float* __restrict__ attout) {
  const int t = threadIdx.x;
  const int lane = t & 63;
  const int wv = t >> 6;
  const int d4 = lane & 3;
  const int c = (lane >> 2) & 3;
  const int sg = lane >> 4;
  const int cdx = c & 1, cdy = c >> 1;

  const int l = blockIdx.x;
  const int h = blockIdx.y * 4 + wv;
  const int b = blockIdx.z;

  const float xf = (float)(l & (WS - 1));
  const float yf = (float)(l >> 6);

  // logits (same address across wave -> broadcast loads)
  const float* lp = attnraw + ((size_t)b * 64 + h * 8) * LTOT + l;
  float lg[NPT];
#pragma unroll
  for (int p = 0; p < NPT; ++p) lg[p] = lp[(size_t)p * LTOT];
  float m = lg[0];
#pragma unroll
  for (int p = 1; p < NPT; ++p) m = fmaxf(m, lg[p]);
  float ssum = 0.0f;
  float ew[NPT];
#pragma unroll
  for (int p = 0; p < NPT; ++p) {
    ew[p] = __expf(lg[p] - m);
    ssum += ew[p];
  }
  const float inv = 1.0f / ssum;

  const float* vb = value + ((size_t)b * NHEAD + h) * (LTOT * DHD);
  const float* ob = offraw + ((size_t)b * CM + h * 16) * LTOT + l;

  float4 o = {0.0f, 0.0f, 0.0f, 0.0f};
#pragma unroll
  for (int it = 0; it < 2; ++it) {
    const int p = sg + 4 * it;
    const float offx = ob[(size_t)(p * 2) * LTOT];
    const float offy = ob[(size_t)(p * 2 + 1) * LTOT];
    const float px = xf + 10.0f * fast_tanh(offx);
    const float py = yf + 10.0f * fast_tanh(offy);
    const float x0f = floorf(px), y0f = floorf(py);
    const float fx = px - x0f, fy = py - y0f;
    const int ix = (int)x0f + cdx;
    const int iy = (int)y0f + cdy;
    const float wx = cdx ? fx : 1.0f - fx;
    const float wy = cdy ? fy : 1.0f - fy;
    const bool valid = ((unsigned)ix < WS) & ((unsigned)iy < HS);
    const float bw = valid ? ew[p] * inv * wx * wy : 0.0f;
    const int cx = min(max(ix, 0), WS - 1);
    const int cy = min(max(iy, 0), HS - 1);
    const float4 v = *(const float4*)(vb + (size_t)((cy << 6) + cx) * DHD + d4 * 4);
    o.x += bw * v.x;
    o.y += bw * v.y;
    o.z += bw * v.z;
    o.w += bw * v.w;
  }

  // reduce over corner bits (4,8) and sample-group bits (16,32)
#pragma unroll
  for (int mask = 4; mask <= 32; mask <<= 1) {
    o.x += __shfl_xor(o.x, mask);
    o.y += __shfl_xor(o.y, mask);
    o.z += __shfl_xor(o.z, mask);
    o.w += __shfl_xor(o.w, mask);
  }

  if (lane < 4) {
    float* op = attout + ((size_t)b * LTOT + l) * CM + h * DHD + lane * 4;
    *(float4*)op = o;
  }
}

extern "C" void kernel_launch(void* const* d_in, const int* in_sizes, int n_in,
                              void* d_out, int out_size, void* d_ws, size_t ws_size,
                              hipStream_t stream) {
  const float* nbr    = (const float*)d_in[0];
  const float* ext    = (const float*)d_in[1];
  const float* W_val  = (const float*)d_in[2];
  const float* b_val  = (const float*)d_in[3];
  const float* W_off  = (const float*)d_in[4];
  const float* b_off  = (const float*)d_in[5];
  const float* W_attn = (const float*)d_in[6];
  const float* b_attn = (const float*)d_in[7];
  const float* W_out  = (const float*)d_in[8];
  const float* b_out  = (const float*)d_in[9];
  float* out = (float*)d_out;

  float* value   = (float*)d_ws;                                // 16 MB [b][h][l][16]
  float* offraw  = value + (size_t)HB * NHEAD * LTOT * DHD;     // 16 MB [b][128][l]
  float* attnraw = offraw + (size_t)HB * CM * LTOT;             // 8 MB  [b][64][l]
  float* attout  = attnraw + (size_t)HB * (NHEAD * NPT) * LTOT; // 16 MB [b][l][128]

  dim3 blk(256);
  gemmv<128, 32, 0, true><<<dim3(LTOT / 256, 4, HB), blk, 0, stream>>>(nbr, W_val, b_val, value);
  gemmv<128, 32, 1, true><<<dim3(LTOT / 256, 4, HB), blk, 0, stream>>>(ext, W_off, b_off, offraw);
  gemmv<64, 16, 1, true><<<dim3(LTOT / 256, 4, HB), blk, 0, stream>>>(ext, W_attn, b_attn, attnraw);
  sampler<<<dim3(LTOT, 2, HB), blk, 0, stream>>>(value, offraw, attnraw, attout);
  gemmv<128, 32, 1, false><<<dim3(LTOT / 256, 4, HB), blk, 0, stream>>>(attout, W_out, b_out, out);
}